// Round 3
// baseline (596.946 us; speedup 1.0000x reference)
//
#include <hip/hip_runtime.h>

// Projection: out[b,f,e] = sum_d x[b, idx[f,d]] * W[f,d,e] + bias[f,e]
// B=524288, F=23, DMAX=4, E=10, TOTAL=65.  W pre-masked past dims[f].
//
// v3b: row-pair float4 stores (v3 + compile fix: __builtin_nontemporal_store
// needs a NATIVE clang vector type, not HIP's float4 class -> use
// ext_vector_type(4) float).
// v2 (row-tiled LDS, float2 stores) reached ~148 us kernel (~3.3 TB/s) vs
// the 6.35 TB/s the harness fill kernel achieves on the same buffer ->
// write-path bound by store width/count. Each thread owns one 16B-aligned
// float4 of a flat row-PAIR (2 rows = 460 floats; pair stride 1840 B is
// 16B-aligned). A float4 spans at most 2 (feature,row) groups: group A =
// element 0's, group B = element 3's; per-element cndmask picks the right
// x-quad. idx/W/bias register-resident for the whole block.
// Stores: 524K nontemporal dwordx4 (1 KB/wave contiguous), half of v2.

#define PROJ_B     524288
#define PROJ_TOTAL 65
#define PROJ_F     23
#define PROJ_DMAX  4
#define PROJ_E     10
#define PROJ_COLS  (PROJ_F * PROJ_E)     // 230
#define PAIR_DW    (2 * PROJ_COLS)       // 460 floats per row-pair
#define PAIR_F4    (PAIR_DW / 4)         // 115 float4 per row-pair
#define ROWS       64                    // rows per block (32 pairs)
#define NPAIR      (ROWS / 2)
#define TILE_DW    (ROWS * PROJ_TOTAL)   // 4160 dwords = 16640 B LDS
#define TILE_F4    (TILE_DW / 4)         // 1040 float4

typedef float f32x4 __attribute__((ext_vector_type(4)));

__global__ __launch_bounds__(256, 4)
void Projection_5171140624940_kernel(const float* __restrict__ x,
                                     const float* __restrict__ W,
                                     const float* __restrict__ bias,
                                     const int*   __restrict__ idx,
                                     float*       __restrict__ out) {
    __shared__ float xs[TILE_DW];

    const int tid = threadIdx.x;
    const long long b0 = (long long)blockIdx.x * ROWS;   // first row of tile

    // ---- stage x tile: contiguous, 16B-aligned (rows packed, 65*4*64 B).
    const f32x4* __restrict__ src = (const f32x4*)(x + b0 * PROJ_TOTAL);
    f32x4* dst = (f32x4*)xs;
    #pragma unroll
    for (int i = 0; i < 4; ++i)
        dst[i * 256 + tid] = src[i * 256 + tid];
    if (tid < TILE_F4 - 4 * 256)                         // 16 remaining
        dst[4 * 256 + tid] = src[4 * 256 + tid];

    // ---- per-thread fixed float4 slot k within a row-pair.
    const int k0 = tid & 127;                            // 0..127
    const int pg = tid >> 7;                             // handles pairs pg, pg+2, ...
    const bool active = (k0 < PAIR_F4);
    const int k  = active ? k0 : (PAIR_F4 - 1);          // clamp for metadata

    // element j covers flat pair-column g = 4k+j -> (row r, col c, feat f, emb e)
    int rj[4], fj[4], ej[4];
    #pragma unroll
    for (int j = 0; j < 4; ++j) {
        const int g = 4 * k + j;
        const int r = (g >= PROJ_COLS) ? 1 : 0;
        const int c = g - PROJ_COLS * r;
        const int f = c / PROJ_E;                        // magic-mul
        rj[j] = r; fj[j] = f; ej[j] = c - f * PROJ_E;
    }
    const int fA = fj[0], rA = rj[0];
    const int fB = fj[3], rB = rj[3];
    bool useB[4];
    #pragma unroll
    for (int j = 0; j < 4; ++j)
        useB[j] = (fj[j] != fA) | (rj[j] != rA);

    // idx/W/bias loaded ONCE per thread (L1-resident), live in registers.
    const int4 idA = *(const int4*)(idx + fA * PROJ_DMAX);
    const int4 idB = *(const int4*)(idx + fB * PROJ_DMAX);
    float w[4][4], bb[4];
    #pragma unroll
    for (int j = 0; j < 4; ++j) {
        const float* __restrict__ Wf = W + fj[j] * (PROJ_DMAX * PROJ_E) + ej[j];
        #pragma unroll
        for (int d = 0; d < 4; ++d) w[j][d] = Wf[d * PROJ_E];
        bb[j] = bias[fj[j] * PROJ_E + ej[j]];
    }

    __syncthreads();

    if (active) {
        #pragma unroll 2
        for (int p = pg; p < NPAIR; p += 2) {
            const float* __restrict__ xA = xs + (2 * p + rA) * PROJ_TOTAL;
            const float* __restrict__ xB = xs + (2 * p + rB) * PROJ_TOTAL;
            const float xa0 = xA[idA.x], xa1 = xA[idA.y],
                        xa2 = xA[idA.z], xa3 = xA[idA.w];
            const float xb0 = xB[idB.x], xb1 = xB[idB.y],
                        xb2 = xB[idB.z], xb3 = xB[idB.w];
            f32x4 o;
            #pragma unroll
            for (int j = 0; j < 4; ++j) {
                const float v0 = useB[j] ? xb0 : xa0;
                const float v1 = useB[j] ? xb1 : xa1;
                const float v2 = useB[j] ? xb2 : xa2;
                const float v3 = useB[j] ? xb3 : xa3;
                o[j] = fmaf(v0, w[j][0], fmaf(v1, w[j][1],
                        fmaf(v2, w[j][2], fmaf(v3, w[j][3], bb[j]))));
            }
            // pair base: (b0 + 2p)*920 B; b0,2p even -> multiple of 1840 -> 16B aligned
            f32x4* optr = (f32x4*)(out + (b0 + 2 * p) * PROJ_COLS) + k;
            __builtin_nontemporal_store(o, optr);        // streaming dwordx4
        }
    }
}

extern "C" void kernel_launch(void* const* d_in, const int* in_sizes, int n_in,
                              void* d_out, int out_size, void* d_ws, size_t ws_size,
                              hipStream_t stream) {
    const float* x    = (const float*)d_in[0];   // (B, 65)
    const float* W    = (const float*)d_in[1];   // (23, 4, 10)
    const float* bias = (const float*)d_in[2];   // (23, 10)
    const int*   idx  = (const int*)d_in[3];     // (23, 4)
    float* out = (float*)d_out;                  // (B, 23, 10)

    const int grid  = PROJ_B / ROWS;             // 8192 blocks
    const int block = 256;

    Projection_5171140624940_kernel<<<grid, block, 0, stream>>>(x, W, bias, idx, out);
}